// Round 10
// baseline (1586.422 us; speedup 1.0000x reference)
//
#include <hip/hip_runtime.h>
#include <math.h>

#define HWQ 625      // 25*25
#define NPOSQ 390625 // 625*625
#define NB 4
#define NCH 1024

typedef __attribute__((ext_vector_type(8))) short bf16x8;
typedef __attribute__((ext_vector_type(4))) float f32x4;

__device__ inline unsigned short f2bf(float x) {
    union { float f; unsigned int u; } c; c.f = x;
    unsigned int u = c.u;
    return (unsigned short)((u + 0x7fffu + ((u >> 16) & 1u)) >> 16); // RNE
}
__device__ inline float bfl(unsigned u) { union { unsigned v; float f; } c; c.v = u << 16; return c.f; }
__device__ inline float bfh(unsigned u) { union { unsigned v; float f; } c; c.v = u & 0xffff0000u; return c.f; }

// ---------------- pack: W1P [9e][9t][20co], W3V [2g][10ci][81], bias dups ----------------
__global__ void pack_misc_kernel(const float* __restrict__ W1, const float* __restrict__ b1,
                                 const float* __restrict__ b2, const float* __restrict__ W3,
                                 float* __restrict__ W1P, float* __restrict__ W3V,
                                 float* __restrict__ bL1, float* __restrict__ bL2)
{
    int t = blockIdx.x * blockDim.x + threadIdx.x;
    if (t < 1620) {
        int co = t % 20; int r = t / 20; int e = r / 9, t34 = r % 9;
        W1P[t] = (co < 10) ? W1[co * 81 + e * 9 + t34] : W1[(co - 10) * 81 + t34 * 9 + e];
    }
    if (t < 1620) { // W3V[(g*10+ci)*81 + tap], tap = e*9+t34; g1 source permuted
        int g = t / 810; int rem = t - g * 810; int ci = rem / 81; int tap = rem - ci * 81;
        W3V[t] = W3[ci * 81 + (g == 0 ? tap : (tap % 9) * 9 + tap / 9)];
    }
    if (t < 20) { bL1[t] = b1[t % 10]; bL2[t] = b2[t % 10]; }
}

// ---------------- pack layer-2 weights into MFMA A-fragment order ----------------
__global__ void pack_mfma_w2_kernel(const float* __restrict__ W2,
                                    unsigned short* __restrict__ Ablob)
{
    int t = blockIdx.x * blockDim.x + threadIdx.x;
    if (t >= 54 * 64) return;
    int frag = t >> 6, lane = t & 63;
    int g = frag / 27; int r1 = frag % 27; int kstep = r1 / 9; int dd = r1 % 9;
    int d3 = dd / 3, d4 = dd % 3;
    int co = lane & 15;
    unsigned short v[8];
#pragma unroll
    for (int j = 0; j < 8; ++j) {
        int k = kstep * 32 + ((lane >> 4) << 3) + j;
        float w = 0.0f;
        if (co < 10 && k < 90) {
            int ci = k / 9, e = k % 9, d1 = e / 3, d2 = e % 3;
            int tap = (g == 0) ? (d1 * 27 + d2 * 9 + d3 * 3 + d4)
                               : (d3 * 27 + d4 * 9 + d1 * 3 + d2);
            w = W2[(co * 10 + ci) * 81 + tap];
        }
        v[j] = f2bf(w);
    }
    uint4 val;
    val.x = (unsigned)v[0] | ((unsigned)v[1] << 16);
    val.y = (unsigned)v[2] | ((unsigned)v[3] << 16);
    val.z = (unsigned)v[4] | ((unsigned)v[5] << 16);
    val.w = (unsigned)v[6] | ((unsigned)v[7] << 16);
    *(uint4*)(Ablob + (size_t)frag * 512 + lane * 8) = val;
}

// ---------------- inverse L2 norms over channel dim ----------------
__global__ void invnorm_kernel(const float* __restrict__ fA, const float* __restrict__ fB,
                               float* __restrict__ invA, float* __restrict__ invB)
{
    int idx = blockIdx.x * blockDim.x + threadIdx.x;
    if (idx >= NB * HWQ) return;
    const float* f = blockIdx.y ? fB : fA;
    float* o = blockIdx.y ? invB : invA;
    int b = idx / HWQ, m = idx - b * HWQ;
    const float* p = f + (size_t)b * NCH * HWQ + m;
    float s = 0.f;
    for (int c = 0; c < NCH; c += 4) {
        float x0 = p[(c + 0) * HWQ], x1 = p[(c + 1) * HWQ];
        float x2 = p[(c + 2) * HWQ], x3 = p[(c + 3) * HWQ];
        s += x0 * x0 + x1 * x1 + x2 * x2 + x3 * x3;
    }
    o[idx] = 1.0f / sqrtf(s + 1e-6f);
}

// ---------------- correlation GEMM ----------------
__global__ __launch_bounds__(256) void corr_gemm_kernel(
    const float* __restrict__ fA, const float* __restrict__ fB,
    const float* __restrict__ invA, const float* __restrict__ invB,
    float* __restrict__ corr)
{
    __shared__ float As[16][64];
    __shared__ float Bs[16][64];
    const int b = blockIdx.z;
    const int m0 = blockIdx.y * 64, n0 = blockIdx.x * 64;
    const int tid = threadIdx.x;
    const int tx = tid & 15, ty = tid >> 4;
    float acc[4][4] = {};
    const float* Ab = fA + (size_t)b * NCH * HWQ;
    const float* Bb = fB + (size_t)b * NCH * HWQ;
    for (int k0 = 0; k0 < NCH; k0 += 16) {
        for (int i = tid; i < 1024; i += 256) {
            int k = i >> 6, mm = i & 63;
            int gm = m0 + mm, gn = n0 + mm;
            As[k][mm] = (gm < HWQ) ? Ab[(k0 + k) * HWQ + gm] : 0.0f;
            Bs[k][mm] = (gn < HWQ) ? Bb[(k0 + k) * HWQ + gn] : 0.0f;
        }
        __syncthreads();
#pragma unroll
        for (int k = 0; k < 16; ++k) {
            float4 a4 = *(const float4*)&As[k][ty * 4];
            float4 b4 = *(const float4*)&Bs[k][tx * 4];
            float av[4] = {a4.x, a4.y, a4.z, a4.w};
            float bv[4] = {b4.x, b4.y, b4.z, b4.w};
#pragma unroll
            for (int i = 0; i < 4; ++i)
#pragma unroll
                for (int j = 0; j < 4; ++j)
                    acc[i][j] = fmaf(av[i], bv[j], acc[i][j]);
        }
        __syncthreads();
    }
#pragma unroll
    for (int i = 0; i < 4; ++i) {
        int m = m0 + ty * 4 + i;
        if (m >= HWQ) continue;
        float ia = invA[b * HWQ + m];
#pragma unroll
        for (int j = 0; j < 4; ++j) {
            int n = n0 + tx * 4 + j;
            if (n >= HWQ) continue;
            float v = acc[i][j] * ia * invB[b * HWQ + n];
            v = fmaxf(v, 0.0f);
            v = v / sqrtf(v * v + 1e-6f);
            corr[((size_t)b * HWQ + m) * HWQ + n] = v;
        }
    }
}

// ---------------- mutual matching helpers ----------------
__global__ void rowmax_kernel(const float* __restrict__ s, float* __restrict__ rmax)
{
    int row = blockIdx.x * 4 + (threadIdx.x >> 6);
    int lane = threadIdx.x & 63;
    if (row >= NB * HWQ) return;
    const float* p = s + (size_t)row * HWQ;
    float v = -1e30f;
    for (int n = lane; n < HWQ; n += 64) v = fmaxf(v, p[n]);
    for (int off = 32; off; off >>= 1) v = fmaxf(v, __shfl_xor(v, off));
    if (lane == 0) rmax[row] = v;
}

__global__ void colmax_kernel(const float* __restrict__ s, float* __restrict__ cmax)
{
    int b = blockIdx.x;
    int col = blockIdx.y * 128 + threadIdx.x;
    if (col >= HWQ) return;
    const float* p = s + (size_t)b * NPOSQ + col;
    float v = -1e30f;
    for (int m = 0; m < HWQ; ++m) v = fmaxf(v, p[m * HWQ]);
    cmax[b * HWQ + col] = v;
}

__global__ void mm_apply_kernel(const float* __restrict__ s, const float* __restrict__ rmax,
                                const float* __restrict__ cmax, float* __restrict__ out)
{
    int idx = blockIdx.x * blockDim.x + threadIdx.x;
    if (idx >= NB * NPOSQ) return;
    int b = idx / NPOSQ, rem = idx - b * NPOSQ;
    int m = rem / HWQ, n = rem - m * HWQ;
    float v = s[idx];
    out[idx] = v * v * v / ((rmax[b * HWQ + m] + 1e-5f) * (cmax[b * HWQ + n] + 1e-5f));
}

// ---------------- layer 1: VALU conv, weights in LDS ----------------
// OUTPUT LAYOUT: x1[f12][co(20)][625]
__global__ __launch_bounds__(192) void conv4d_l1(
    const float* __restrict__ corr, const float* __restrict__ W1P,
    const float* __restrict__ bL1, unsigned short* __restrict__ x1)
{
    __shared__ float sp[9 * 784]; // 9 x 28 x 28
    __shared__ float wl[1620];
    const int f12 = blockIdx.x;
    const float* in = corr + (size_t)blockIdx.z * NPOSQ;
    unsigned short* out = x1 + (size_t)blockIdx.z * 20 * NPOSQ;
    const int f1 = f12 / 25, f2 = f12 - f1 * 25;
    const int tid = threadIdx.x;

    for (int i = tid; i < 9 * 784; i += 192) sp[i] = 0.0f;
    for (int i = tid; i < 1620; i += 192) wl[i] = W1P[i];

    const int tt = (tid < 169) ? tid : 0;
    const int ty = tt / 13, tx = tt - ty * 13;
    const int r0 = ty * 2, c0 = tx * 2;

    float acc[20][4];
#pragma unroll
    for (int co = 0; co < 20; ++co) {
        float bv = bL1[co];
        acc[co][0] = bv; acc[co][1] = bv; acc[co][2] = bv; acc[co][3] = bv;
    }

    __syncthreads();
    for (int i = tid; i < 5625; i += 192) {
        int e = i / 625, q = i - e * 625;
        int d1 = e / 3, d2 = e - d1 * 3;
        int f1n = f1 + d1 - 1, f2n = f2 + d2 - 1;
        float v = 0.0f;
        if (((unsigned)f1n < 25u) & ((unsigned)f2n < 25u))
            v = in[(f1n * 25 + f2n) * HWQ + q];
        int rr = q / 25, cc = q - rr * 25;
        sp[e * 784 + (rr + 1) * 28 + (cc + 1)] = v;
    }
    __syncthreads();

#pragma unroll 1
    for (int e = 0; e < 9; ++e) {
        float win[16];
        const int base = e * 784 + r0 * 28 + c0;
#pragma unroll
        for (int a = 0; a < 4; ++a)
#pragma unroll
            for (int bb = 0; bb < 4; ++bb)
                win[a * 4 + bb] = sp[base + a * 28 + bb];
#pragma unroll
        for (int t34 = 0; t34 < 9; ++t34) {
            int d3 = t34 / 3, d4 = t34 - d3 * 3;
            float x0 = win[d3 * 4 + d4], x1v = win[d3 * 4 + d4 + 1];
            float x2v = win[(d3 + 1) * 4 + d4], x3v = win[(d3 + 1) * 4 + d4 + 1];
            const float* wp = wl + (e * 9 + t34) * 20;
#pragma unroll
            for (int c4 = 0; c4 < 5; ++c4) {
                float4 w4 = *(const float4*)(wp + c4 * 4);
                float wv[4] = {w4.x, w4.y, w4.z, w4.w};
#pragma unroll
                for (int q4 = 0; q4 < 4; ++q4) {
                    int co = c4 * 4 + q4;
                    acc[co][0] = fmaf(x0, wv[q4], acc[co][0]);
                    acc[co][1] = fmaf(x1v, wv[q4], acc[co][1]);
                    acc[co][2] = fmaf(x2v, wv[q4], acc[co][2]);
                    acc[co][3] = fmaf(x3v, wv[q4], acc[co][3]);
                }
            }
        }
    }

    if (tid < 169) {
        unsigned short* ob = out + (size_t)f12 * 20 * 625;
#pragma unroll
        for (int co = 0; co < 20; ++co) {
            unsigned short* op = ob + co * 625;
#pragma unroll
            for (int i = 0; i < 2; ++i)
#pragma unroll
                for (int j = 0; j < 2; ++j) {
                    int f3 = r0 + i, f4 = c0 + j;
                    if (f3 < 25 && f4 < 25)
                        op[f3 * 25 + f4] = f2bf(fmaxf(acc[co][i * 2 + j], 0.0f));
                }
        }
    }
}

// ---------------- layer 2: MFMA conv with T14 async-stage ----------------
// Activations [f12][ch][625]. LDS halo rows qp=u*27+v, 736 x 36 kslots bf16.
// Per kstep: write prefetched regs -> LDS; barrier; load 9 A-frags (oldest ->
// their vmcnt waits don't drain newer stage loads, m135); issue stage loads for
// kstep+1 (consumed at next iter's write, latency hidden under MFMA); MFMA with
// compile-time dd displacement (d3*27+d4)*72B.
#define L2S 36
#define L2ROWS 736

#define L2_CALC(KS)                                                         \
    {                                                                       \
        int ksb = (KS) * 32;                                                \
        _Pragma("unroll")                                                   \
        for (int i2 = 0; i2 < 4; ++i2) {                                    \
            int cie = ksb + wave * 4 + i2;                                  \
            int ci = cie / 9, e = cie - ci * 9;                             \
            int f1n = f1 + e / 3 - 1, f2n = f2 + (e - (e / 3) * 3) - 1;     \
            bool valid = (cie < 90) & ((unsigned)f1n < 25u) & ((unsigned)f2n < 25u); \
            int pidx = valid ? ((f1n * 25 + f2n) * 20 + g * 10 + ci) : 0;   \
            gpp[i2] = in + (size_t)pidx * 625;                              \
            vld[i2] = valid;                                                \
        }                                                                   \
    }

#define L2_LOAD()                                                           \
    _Pragma("unroll")                                                       \
    for (int pass = 0; pass < 10; ++pass) {                                 \
        if (pass < 9 || lane < 49) {                                        \
            int q = pass * 64 + lane;                                       \
            vreg[pass][0] = vld[0] ? gpp[0][q] : (unsigned short)0;         \
            vreg[pass][1] = vld[1] ? gpp[1][q] : (unsigned short)0;         \
            vreg[pass][2] = vld[2] ? gpp[2][q] : (unsigned short)0;         \
            vreg[pass][3] = vld[3] ? gpp[3][q] : (unsigned short)0;         \
        }                                                                   \
    }

__global__ __launch_bounds__(512) void conv4d_mfma_l2(
    const unsigned short* __restrict__ x1, const unsigned short* __restrict__ Ablob,
    const float* __restrict__ bL2, unsigned short* __restrict__ x2)
{
    __shared__ alignas(16) unsigned short sp[L2ROWS * L2S]; // 52992 B
    const int f12 = blockIdx.x, g = blockIdx.y;
    const unsigned short* in = x1 + (size_t)blockIdx.z * 20 * NPOSQ;
    unsigned short* out = x2 + (size_t)blockIdx.z * 20 * NPOSQ;
    const int f1 = f12 / 25, f2 = f12 - f1 * 25;
    const int tid = threadIdx.x, wave = tid >> 6, lane = tid & 63;
    const int lo16 = lane & 15, kqg = (lane >> 4) << 3;

    for (int i = tid; i < L2ROWS * L2S / 2; i += 512) ((unsigned*)sp)[i] = 0u;

    f32x4 acc[7];
#pragma unroll
    for (int j = 0; j < 7; ++j) acc[j] = (f32x4){0.f, 0.f, 0.f, 0.f};
    const unsigned short* Ag = Ablob + (size_t)g * 27 * 512;

    int dstw_[10];
#pragma unroll
    for (int pass = 0; pass < 10; ++pass) {
        int idx = pass * 64 + lane;
        int rr = idx / 25, cc = idx - rr * 25;
        dstw_[pass] = ((rr + 1) * 27 + cc + 1) * (L2S * 2) + wave * 8;
    }
    unsigned bpo_[7];
#pragma unroll
    for (int j = 0; j < 7; ++j) {
        int t = wave + j * 8;
        int f3 = t >> 1, h = t & 1;
        bpo_[j] = (unsigned)(((f3 * 27 + h * 16 + lo16) * L2S + kqg) * 2);
    }

    const unsigned short* gpp[4];
    bool vld[4];
    unsigned short vreg[10][4];

    L2_CALC(0);
    L2_LOAD();

#pragma unroll 1
    for (int kstep = 0; kstep < 3; ++kstep) {
        __syncthreads();
#pragma unroll
        for (int pass = 0; pass < 10; ++pass) {
            if (pass < 9 || lane < 49) {
                uint2 w;
                w.x = (unsigned)vreg[pass][0] | ((unsigned)vreg[pass][1] << 16);
                w.y = (unsigned)vreg[pass][2] | ((unsigned)vreg[pass][3] << 16);
                *(uint2*)((char*)sp + dstw_[pass]) = w;
            }
        }
        __syncthreads();
        const unsigned short* Abase = Ag + (size_t)(kstep * 9) * 512 + lane * 8;
        bf16x8 af[9];
#pragma unroll
        for (int dd = 0; dd < 9; ++dd)
            af[dd] = *(const bf16x8*)(Abase + dd * 512);
        if (kstep < 2) {
            L2_CALC(kstep + 1);
            L2_LOAD();
        }
#pragma unroll
        for (int dd = 0; dd < 9; ++dd) {
            const int d3 = dd / 3, d4 = dd - d3 * 3;
            const int imm = (d3 * 27 + d4) * (L2S * 2);
#pragma unroll
            for (int j = 0; j < 7; ++j) {
                if (j < 6 || wave < 2) {
                    const char* rp = (const char*)sp + (bpo_[j] + imm);
                    uint2 p0 = *(const uint2*)rp;
                    uint2 p1 = *(const uint2*)(rp + 8);
                    union { unsigned u[4]; bf16x8 v; } cv;
                    cv.u[0] = p0.x; cv.u[1] = p0.y; cv.u[2] = p1.x; cv.u[3] = p1.y;
                    acc[j] = __builtin_amdgcn_mfma_f32_16x16x32_bf16(af[dd], cv.v, acc[j], 0, 0, 0);
                }
            }
        }
    }

    unsigned short* ob = out + (size_t)f12 * 20 * 625 + g * 10 * 625;
    int t = wave;
    for (int j = 0; j < 7; ++j, t += 8) {
        if (t < 50) {
            int f3 = t >> 1, h = t & 1;
            int f4 = h * 16 + lo16;
            if (f4 < 25) {
#pragma unroll
                for (int r = 0; r < 4; ++r) {
                    int co = (lane >> 4) * 4 + r;
                    if (co < 10) {
                        float v = acc[j][r] + bL2[g * 10 + co];
                        ob[co * 625 + f3 * 25 + f4] = f2bf(fmaxf(v, 0.0f));
                    }
                }
            }
        }
    }
}

// ---------------- layer 3: VALU conv (2 outputs only -> MFMA was 2/16 M-util) ----
// Both groups fused; bf16 halo planes in LDS; fused relu-sum to fp32 sbuf.
__global__ __launch_bounds__(192) void conv4d_l3_valu(
    const unsigned short* __restrict__ x2, const float* __restrict__ W3V,
    const float* __restrict__ b3p, float* __restrict__ sbuf)
{
    __shared__ unsigned short spb[2 * 9 * 784]; // 28224 B, bf16 halo planes
    __shared__ float wl[1620];
    const int f12 = blockIdx.x;
    const unsigned short* in = x2 + (size_t)blockIdx.z * 20 * NPOSQ;
    float* out = sbuf + (size_t)blockIdx.z * NPOSQ;
    const int f1 = f12 / 25, f2 = f12 - f1 * 25;
    const int tid = threadIdx.x;

    for (int i = tid; i < 2 * 9 * 784; i += 192) spb[i] = 0;
    for (int i = tid; i < 1620; i += 192) wl[i] = W3V[i];

    const int tt = (tid < 169) ? tid : 0;
    const int ty = tt / 13, tx = tt - ty * 13;
    const int r0 = ty * 2, c0 = tx * 2;

    float acc0[4] = {0.f, 0.f, 0.f, 0.f}, acc1[4] = {0.f, 0.f, 0.f, 0.f};

#pragma unroll 1
    for (int ci = 0; ci < 10; ++ci) {
        __syncthreads();
        for (int i = tid; i < 11250; i += 192) {
            int plane = i / 625, q = i - plane * 625;
            int gg = plane / 9, e = plane - gg * 9;
            int d1 = e / 3, d2 = e - d1 * 3;
            int f1n = f1 + d1 - 1, f2n = f2 + d2 - 1;
            unsigned short v = 0;
            if (((unsigned)f1n < 25u) & ((unsigned)f2n < 25u))
                v = in[((size_t)(f1n * 25 + f2n) * 20 + gg * 10 + ci) * 625 + q];
            int rr = q / 25, cc = q - rr * 25;
            spb[plane * 784 + (rr + 1) * 28 + cc + 1] = v;
        }
        __syncthreads();
        const float* w0p = wl + ci * 81;
        const float* w1p = wl + (10 + ci) * 81;
#pragma unroll 1
        for (int e = 0; e < 9; ++e) {
            float wa[16], wb[16];
            const int base = e * 784 + r0 * 28 + c0; // even -> 4B-aligned uint reads
            const unsigned* pA = (const unsigned*)(spb + base);
            const unsigned* pB = (const unsigned*)(spb + 9 * 784 + base);
#pragma unroll
            for (int a = 0; a < 4; ++a) {
                unsigned uA0 = pA[a * 14], uA1 = pA[a * 14 + 1];
                unsigned uB0 = pB[a * 14], uB1 = pB[a * 14 + 1];
                wa[a * 4 + 0] = bfl(uA0); wa[a * 4 + 1] = bfh(uA0);
                wa[a * 4 + 2] = bfl(uA1); wa[a * 4 + 3] = bfh(uA1);
                wb[a * 4 + 0] = bfl(uB0); wb[a * 4 + 1] = bfh(uB0);
                wb[a * 4 + 2] = bfl(uB1); wb[a * 4 + 3] = bfh(uB1);
            }
#pragma unroll
            for (int t34 = 0; t34 < 9; ++t34) {
                int d3 = t34 / 3, d4 = t34 - d3 * 3;
                float g0w = w0p[e * 9 + t34];
                float g1w = w1p[e * 9 + t34];
                acc0[0] = fmaf(wa[d3 * 4 + d4],           g0w, acc0[0]);
                acc0[1] = fmaf(wa[d3 * 4 + d4 + 1],       g0w, acc0[1]);
                acc0[2] = fmaf(wa[(d3 + 1) * 4 + d4],     g0w, acc0[2]);
                acc0[3] = fmaf(wa[(d3 + 1) * 4 + d4 + 1], g0w, acc0[3]);
                acc1[0] = fmaf(wb[d3 * 4 + d4],           g1w, acc1[0]);
                acc1[1] = fmaf(wb[d3 * 4 + d4 + 1],       g1w, acc1[1]);
                acc1[2] = fmaf(wb[(d3 + 1) * 4 + d4],     g1w, acc1[2]);
                acc1[3] = fmaf(wb[(d3 + 1) * 4 + d4 + 1], g1w, acc1[3]);
            }
        }
    }

    const float b3v = b3p[0];
    if (tid < 169) {
#pragma unroll
        for (int i = 0; i < 2; ++i)
#pragma unroll
            for (int j = 0; j < 2; ++j) {
                int f3 = r0 + i, f4 = c0 + j;
                if (f3 < 25 && f4 < 25) {
                    int qi = i * 2 + j;
                    out[f12 * 625 + f3 * 25 + f4] =
                        fmaxf(acc0[qi] + b3v, 0.0f) + fmaxf(acc1[qi] + b3v, 0.0f);
                }
            }
    }
}

// ---------------- launch ----------------
extern "C" void kernel_launch(void* const* d_in, const int* in_sizes, int n_in,
                              void* d_out, int out_size, void* d_ws, size_t ws_size,
                              hipStream_t stream)
{
    const float* fA = (const float*)d_in[0];
    const float* fB = (const float*)d_in[1];
    const float* W1 = (const float*)d_in[2];
    const float* b1 = (const float*)d_in[3];
    const float* W2 = (const float*)d_in[4];
    const float* b2 = (const float*)d_in[5];
    const float* W3 = (const float*)d_in[6];
    const float* b3 = (const float*)d_in[7];
    float* out = (float*)d_out;
    float* ws = (float*)d_ws;

    float* invA = ws + 0;        // 2500
    float* invB = ws + 2500;     // 2500
    float* rmax = ws + 5000;     // 2500
    float* cmax = ws + 7500;     // 2500
    float* W1P  = ws + 10000;    // 1620
    float* bL1  = ws + 11620;    // 20
    float* bL2  = ws + 11640;    // 20
    unsigned short* Ablob2 = (unsigned short*)(ws + 12000); // 27648 us
    float* W3V  = ws + 25824;    // 1620
    float* corr = ws + 40000;    // 1562500
    float* sbuf = ws + 1602500;  // 1562500
    unsigned short* x1b = (unsigned short*)(ws + 3165000);

    const size_t REQ = (size_t)34415000 * 4;
    const bool fused = ws_size >= REQ;
    unsigned short* x2b = fused ? (unsigned short*)(ws + 18790000)
                                : (unsigned short*)(ws + 7080000);

    hipLaunchKernelGGL(pack_misc_kernel, dim3(7), dim3(256), 0, stream,
                       W1, b1, b2, W3, W1P, W3V, bL1, bL2);
    hipLaunchKernelGGL(pack_mfma_w2_kernel, dim3(14), dim3(256), 0, stream, W2, Ablob2);
    hipLaunchKernelGGL(invnorm_kernel, dim3(10, 2), dim3(256), 0, stream, fA, fB, invA, invB);
    hipLaunchKernelGGL(corr_gemm_kernel, dim3(10, 10, 4), dim3(256), 0, stream,
                       fA, fB, invA, invB, corr);
    hipLaunchKernelGGL(rowmax_kernel, dim3(625), dim3(256), 0, stream, corr, rmax);
    hipLaunchKernelGGL(colmax_kernel, dim3(4, 5), dim3(128), 0, stream, corr, cmax);
    hipLaunchKernelGGL(mm_apply_kernel, dim3(6104), dim3(256), 0, stream, corr, rmax, cmax, corr);

    if (fused) {
        hipLaunchKernelGGL(conv4d_l1, dim3(625, 1, NB), dim3(192), 0, stream, corr, W1P, bL1, x1b);
        hipLaunchKernelGGL(conv4d_mfma_l2, dim3(625, 2, NB), dim3(512), 0, stream,
                           x1b, Ablob2, bL2, x2b);
        hipLaunchKernelGGL(conv4d_l3_valu, dim3(625, 1, NB), dim3(192), 0, stream,
                           x2b, W3V, b3, sbuf);
    } else {
        for (int b = 0; b < NB; ++b) {
            hipLaunchKernelGGL(conv4d_l1, dim3(625, 1, 1), dim3(192), 0, stream,
                               corr + (size_t)b * NPOSQ, W1P, bL1, x1b);
            hipLaunchKernelGGL(conv4d_mfma_l2, dim3(625, 2, 1), dim3(512), 0, stream,
                               x1b, Ablob2, bL2, x2b);
            hipLaunchKernelGGL(conv4d_l3_valu, dim3(625, 1, 1), dim3(192), 0, stream,
                               x2b, W3V, b3, sbuf + (size_t)b * NPOSQ);
        }
    }

    hipLaunchKernelGGL(rowmax_kernel, dim3(625), dim3(256), 0, stream, sbuf, rmax);
    hipLaunchKernelGGL(colmax_kernel, dim3(4, 5), dim3(128), 0, stream, sbuf, cmax);
    hipLaunchKernelGGL(mm_apply_kernel, dim3(6104), dim3(256), 0, stream, sbuf, rmax, cmax, out);
}

// Round 11
// 1109.848 us; speedup vs baseline: 1.4294x; 1.4294x over previous
//
#include <hip/hip_runtime.h>
#include <math.h>

#define HWQ 625      // 25*25
#define NPOSQ 390625 // 625*625
#define NB 4
#define NCH 1024

typedef __attribute__((ext_vector_type(8))) short bf16x8;
typedef __attribute__((ext_vector_type(4))) float f32x4;

__device__ inline unsigned short f2bf(float x) {
    union { float f; unsigned int u; } c; c.f = x;
    unsigned int u = c.u;
    return (unsigned short)((u + 0x7fffu + ((u >> 16) & 1u)) >> 16); // RNE
}

// ---------------- pack: W1P [9e][9t][20co], bias dups ----------------
__global__ void pack_misc_kernel(const float* __restrict__ W1, const float* __restrict__ b1,
                                 const float* __restrict__ b2,
                                 float* __restrict__ W1P, float* __restrict__ bL1,
                                 float* __restrict__ bL2)
{
    int t = blockIdx.x * blockDim.x + threadIdx.x;
    if (t < 1620) {
        int co = t % 20; int r = t / 20; int e = r / 9, t34 = r % 9;
        W1P[t] = (co < 10) ? W1[co * 81 + e * 9 + t34] : W1[(co - 10) * 81 + t34 * 9 + e];
    }
    if (t < 20) { bL1[t] = b1[t % 10]; bL2[t] = b2[t % 10]; }
}

// ---------------- pack layer-2 weights into MFMA A-fragment order ----------------
__global__ void pack_mfma_w2_kernel(const float* __restrict__ W2,
                                    unsigned short* __restrict__ Ablob)
{
    int t = blockIdx.x * blockDim.x + threadIdx.x;
    if (t >= 54 * 64) return;
    int frag = t >> 6, lane = t & 63;
    int g = frag / 27; int r1 = frag % 27; int kstep = r1 / 9; int dd = r1 % 9;
    int d3 = dd / 3, d4 = dd % 3;
    int co = lane & 15;
    unsigned short v[8];
#pragma unroll
    for (int j = 0; j < 8; ++j) {
        int k = kstep * 32 + ((lane >> 4) << 3) + j;
        float w = 0.0f;
        if (co < 10 && k < 90) {
            int ci = k / 9, e = k % 9, d1 = e / 3, d2 = e % 3;
            int tap = (g == 0) ? (d1 * 27 + d2 * 9 + d3 * 3 + d4)
                               : (d3 * 27 + d4 * 9 + d1 * 3 + d2);
            w = W2[(co * 10 + ci) * 81 + tap];
        }
        v[j] = f2bf(w);
    }
    uint4 val;
    val.x = (unsigned)v[0] | ((unsigned)v[1] << 16);
    val.y = (unsigned)v[2] | ((unsigned)v[3] << 16);
    val.z = (unsigned)v[4] | ((unsigned)v[5] << 16);
    val.w = (unsigned)v[6] | ((unsigned)v[7] << 16);
    *(uint4*)(Ablob + (size_t)frag * 512 + lane * 8) = val;
}

// ---------------- pack layer-3 weights: K=180 (both groups), rows 0/1 ----------------
__global__ void pack_mfma_w3_kernel(const float* __restrict__ W3,
                                    unsigned short* __restrict__ Ablob3)
{
    int t = blockIdx.x * blockDim.x + threadIdx.x;
    if (t >= 54 * 64) return;
    int frag = t >> 6, lane = t & 63;
    int kstep = frag / 9, dd = frag % 9;
    int d3 = dd / 3, d4 = dd % 3;
    int row = lane & 15;
    unsigned short v[8];
#pragma unroll
    for (int j = 0; j < 8; ++j) {
        int k = kstep * 32 + ((lane >> 4) << 3) + j;
        float w = 0.0f;
        if (k < 180) {
            int g = k / 90, rem = k - g * 90;
            int ci = rem / 9, e = rem % 9;
            if (row == g) {
                int d1 = e / 3, d2 = e % 3;
                int tap = (g == 0) ? (d1 * 27 + d2 * 9 + d3 * 3 + d4)
                                   : (d3 * 27 + d4 * 9 + d1 * 3 + d2);
                w = W3[ci * 81 + tap];
            }
        }
        v[j] = f2bf(w);
    }
    uint4 val;
    val.x = (unsigned)v[0] | ((unsigned)v[1] << 16);
    val.y = (unsigned)v[2] | ((unsigned)v[3] << 16);
    val.z = (unsigned)v[4] | ((unsigned)v[5] << 16);
    val.w = (unsigned)v[6] | ((unsigned)v[7] << 16);
    *(uint4*)(Ablob3 + (size_t)frag * 512 + lane * 8) = val;
}

// ---------------- inverse L2 norms over channel dim ----------------
__global__ void invnorm_kernel(const float* __restrict__ fA, const float* __restrict__ fB,
                               float* __restrict__ invA, float* __restrict__ invB)
{
    int idx = blockIdx.x * blockDim.x + threadIdx.x;
    if (idx >= NB * HWQ) return;
    const float* f = blockIdx.y ? fB : fA;
    float* o = blockIdx.y ? invB : invA;
    int b = idx / HWQ, m = idx - b * HWQ;
    const float* p = f + (size_t)b * NCH * HWQ + m;
    float s = 0.f;
    for (int c = 0; c < NCH; c += 4) {
        float x0 = p[(c + 0) * HWQ], x1 = p[(c + 1) * HWQ];
        float x2 = p[(c + 2) * HWQ], x3 = p[(c + 3) * HWQ];
        s += x0 * x0 + x1 * x1 + x2 * x2 + x3 * x3;
    }
    o[idx] = 1.0f / sqrtf(s + 1e-6f);
}

// ---------------- correlation GEMM ----------------
__global__ __launch_bounds__(256) void corr_gemm_kernel(
    const float* __restrict__ fA, const float* __restrict__ fB,
    const float* __restrict__ invA, const float* __restrict__ invB,
    float* __restrict__ corr)
{
    __shared__ float As[16][64];
    __shared__ float Bs[16][64];
    const int b = blockIdx.z;
    const int m0 = blockIdx.y * 64, n0 = blockIdx.x * 64;
    const int tid = threadIdx.x;
    const int tx = tid & 15, ty = tid >> 4;
    float acc[4][4] = {};
    const float* Ab = fA + (size_t)b * NCH * HWQ;
    const float* Bb = fB + (size_t)b * NCH * HWQ;
    for (int k0 = 0; k0 < NCH; k0 += 16) {
        for (int i = tid; i < 1024; i += 256) {
            int k = i >> 6, mm = i & 63;
            int gm = m0 + mm, gn = n0 + mm;
            As[k][mm] = (gm < HWQ) ? Ab[(k0 + k) * HWQ + gm] : 0.0f;
            Bs[k][mm] = (gn < HWQ) ? Bb[(k0 + k) * HWQ + gn] : 0.0f;
        }
        __syncthreads();
#pragma unroll
        for (int k = 0; k < 16; ++k) {
            float4 a4 = *(const float4*)&As[k][ty * 4];
            float4 b4 = *(const float4*)&Bs[k][tx * 4];
            float av[4] = {a4.x, a4.y, a4.z, a4.w};
            float bv[4] = {b4.x, b4.y, b4.z, b4.w};
#pragma unroll
            for (int i = 0; i < 4; ++i)
#pragma unroll
                for (int j = 0; j < 4; ++j)
                    acc[i][j] = fmaf(av[i], bv[j], acc[i][j]);
        }
        __syncthreads();
    }
#pragma unroll
    for (int i = 0; i < 4; ++i) {
        int m = m0 + ty * 4 + i;
        if (m >= HWQ) continue;
        float ia = invA[b * HWQ + m];
#pragma unroll
        for (int j = 0; j < 4; ++j) {
            int n = n0 + tx * 4 + j;
            if (n >= HWQ) continue;
            float v = acc[i][j] * ia * invB[b * HWQ + n];
            v = fmaxf(v, 0.0f);
            v = v / sqrtf(v * v + 1e-6f);
            corr[((size_t)b * HWQ + m) * HWQ + n] = v;
        }
    }
}

// ---------------- mutual matching helpers ----------------
__global__ void rowmax_kernel(const float* __restrict__ s, float* __restrict__ rmax)
{
    int row = blockIdx.x * 4 + (threadIdx.x >> 6);
    int lane = threadIdx.x & 63;
    if (row >= NB * HWQ) return;
    const float* p = s + (size_t)row * HWQ;
    float v = -1e30f;
    for (int n = lane; n < HWQ; n += 64) v = fmaxf(v, p[n]);
    for (int off = 32; off; off >>= 1) v = fmaxf(v, __shfl_xor(v, off));
    if (lane == 0) rmax[row] = v;
}

__global__ void colmax_kernel(const float* __restrict__ s, float* __restrict__ cmax)
{
    int b = blockIdx.x;
    int col = blockIdx.y * 128 + threadIdx.x;
    if (col >= HWQ) return;
    const float* p = s + (size_t)b * NPOSQ + col;
    float v = -1e30f;
    for (int m = 0; m < HWQ; ++m) v = fmaxf(v, p[m * HWQ]);
    cmax[b * HWQ + col] = v;
}

__global__ void mm_apply_kernel(const float* __restrict__ s, const float* __restrict__ rmax,
                                const float* __restrict__ cmax, float* __restrict__ out)
{
    int idx = blockIdx.x * blockDim.x + threadIdx.x;
    if (idx >= NB * NPOSQ) return;
    int b = idx / NPOSQ, rem = idx - b * NPOSQ;
    int m = rem / HWQ, n = rem - m * HWQ;
    float v = s[idx];
    out[idx] = v * v * v / ((rmax[b * HWQ + m] + 1e-5f) * (cmax[b * HWQ + n] + 1e-5f));
}

// ---------------- layer 1: VALU conv, weights in LDS ----------------
// OUTPUT LAYOUT: x1[f12][co(20)][625]
__global__ __launch_bounds__(192) void conv4d_l1(
    const float* __restrict__ corr, const float* __restrict__ W1P,
    const float* __restrict__ bL1, unsigned short* __restrict__ x1)
{
    __shared__ float sp[9 * 784]; // 9 x 28 x 28
    __shared__ float wl[1620];
    const int f12 = blockIdx.x;
    const float* in = corr + (size_t)blockIdx.z * NPOSQ;
    unsigned short* out = x1 + (size_t)blockIdx.z * 20 * NPOSQ;
    const int f1 = f12 / 25, f2 = f12 - f1 * 25;
    const int tid = threadIdx.x;

    for (int i = tid; i < 9 * 784; i += 192) sp[i] = 0.0f;
    for (int i = tid; i < 1620; i += 192) wl[i] = W1P[i];

    const int tt = (tid < 169) ? tid : 0;
    const int ty = tt / 13, tx = tt - ty * 13;
    const int r0 = ty * 2, c0 = tx * 2;

    float acc[20][4];
#pragma unroll
    for (int co = 0; co < 20; ++co) {
        float bv = bL1[co];
        acc[co][0] = bv; acc[co][1] = bv; acc[co][2] = bv; acc[co][3] = bv;
    }

    __syncthreads();
    for (int i = tid; i < 5625; i += 192) {
        int e = i / 625, q = i - e * 625;
        int d1 = e / 3, d2 = e - d1 * 3;
        int f1n = f1 + d1 - 1, f2n = f2 + d2 - 1;
        float v = 0.0f;
        if (((unsigned)f1n < 25u) & ((unsigned)f2n < 25u))
            v = in[(f1n * 25 + f2n) * HWQ + q];
        int rr = q / 25, cc = q - rr * 25;
        sp[e * 784 + (rr + 1) * 28 + (cc + 1)] = v;
    }
    __syncthreads();

#pragma unroll 1
    for (int e = 0; e < 9; ++e) {
        float win[16];
        const int base = e * 784 + r0 * 28 + c0;
#pragma unroll
        for (int a = 0; a < 4; ++a)
#pragma unroll
            for (int bb = 0; bb < 4; ++bb)
                win[a * 4 + bb] = sp[base + a * 28 + bb];
#pragma unroll
        for (int t34 = 0; t34 < 9; ++t34) {
            int d3 = t34 / 3, d4 = t34 - d3 * 3;
            float x0 = win[d3 * 4 + d4], x1v = win[d3 * 4 + d4 + 1];
            float x2v = win[(d3 + 1) * 4 + d4], x3v = win[(d3 + 1) * 4 + d4 + 1];
            const float* wp = wl + (e * 9 + t34) * 20;
#pragma unroll
            for (int c4 = 0; c4 < 5; ++c4) {
                float4 w4 = *(const float4*)(wp + c4 * 4);
                float wv[4] = {w4.x, w4.y, w4.z, w4.w};
#pragma unroll
                for (int q4 = 0; q4 < 4; ++q4) {
                    int co = c4 * 4 + q4;
                    acc[co][0] = fmaf(x0, wv[q4], acc[co][0]);
                    acc[co][1] = fmaf(x1v, wv[q4], acc[co][1]);
                    acc[co][2] = fmaf(x2v, wv[q4], acc[co][2]);
                    acc[co][3] = fmaf(x3v, wv[q4], acc[co][3]);
                }
            }
        }
    }

    if (tid < 169) {
        unsigned short* ob = out + (size_t)f12 * 20 * 625;
#pragma unroll
        for (int co = 0; co < 20; ++co) {
            unsigned short* op = ob + co * 625;
#pragma unroll
            for (int i = 0; i < 2; ++i)
#pragma unroll
                for (int j = 0; j < 2; ++j) {
                    int f3 = r0 + i, f4 = c0 + j;
                    if (f3 < 25 && f4 < 25)
                        op[f3 * 25 + f4] = f2bf(fmaxf(acc[co][i * 2 + j], 0.0f));
                }
        }
    }
}

// ---------------- MFMA conv core (layers 2 & 3), T14 async-stage ----------------
// Activations [f12][ch][625]. LDS halo rows qp=u*27+v, 736 x 36 kslots bf16.
// Per kstep: write prefetched regs -> LDS; barrier; load 9 A-frags (oldest, so
// MFMA's counted vmcnt wait doesn't drain newer loads, m135); issue next-kstep
// stage loads into regs (latency hidden under MFMA burst); MFMA with
// compile-time dd displacement (d3*27+d4)*72B.
// NOTE: no min-waves in launch_bounds (",6" forced 40-VGPR budget -> spill, R5/R6).
#define L2S 36
#define L2ROWS 736

#define MF_PRE()                                                            \
    int dstw_[10];                                                          \
    _Pragma("unroll")                                                       \
    for (int pass = 0; pass < 10; ++pass) {                                 \
        int idx = pass * 64 + lane;                                         \
        int rr = idx / 25, cc = idx - rr * 25;                              \
        dstw_[pass] = ((rr + 1) * 27 + cc + 1) * (L2S * 2) + wave * 8;      \
    }                                                                       \
    unsigned bpo_[7];                                                       \
    _Pragma("unroll")                                                       \
    for (int j = 0; j < 7; ++j) {                                           \
        int t = wave + j * 8;                                               \
        int f3 = t >> 1, h = t & 1;                                         \
        bpo_[j] = (unsigned)(((f3 * 27 + h * 16 + lo16) * L2S + kqg) * 2);  \
    }                                                                       \
    const unsigned short* gpp[4];                                           \
    bool vld[4];                                                            \
    unsigned short vreg[10][4];

// compute plane descriptors for kstep KS. Channel index in [f12][ch][625] slab
// is cie/9 + CHOFF (L2: cie = ci*9+e, ch = g*10+ci -> CHOFF=g*10;
// L3: cie = g*90+ci*9+e -> cie/9 = g*10+ci, CHOFF=0).
#define MF_CALC(KS, CHOFF, CIE_MAX)                                         \
    {                                                                       \
        int ksb = (KS) * 32;                                                \
        _Pragma("unroll")                                                   \
        for (int i2 = 0; i2 < 4; ++i2) {                                    \
            int cie = ksb + wave * 4 + i2;                                  \
            int e = cie % 9;                                                \
            int f1n = f1 + e / 3 - 1, f2n = f2 + (e - (e / 3) * 3) - 1;     \
            bool valid = (cie < (CIE_MAX)) & ((unsigned)f1n < 25u) & ((unsigned)f2n < 25u); \
            int pidx = valid ? ((f1n * 25 + f2n) * 20 + (CHOFF) + cie / 9) : 0; \
            gpp[i2] = in + (size_t)pidx * 625;                              \
            vld[i2] = valid;                                                \
        }                                                                   \
    }

#define MF_LOAD()                                                           \
    _Pragma("unroll")                                                       \
    for (int pass = 0; pass < 10; ++pass) {                                 \
        if (pass < 9 || lane < 49) {                                        \
            int q = pass * 64 + lane;                                       \
            vreg[pass][0] = vld[0] ? gpp[0][q] : (unsigned short)0;         \
            vreg[pass][1] = vld[1] ? gpp[1][q] : (unsigned short)0;         \
            vreg[pass][2] = vld[2] ? gpp[2][q] : (unsigned short)0;         \
            vreg[pass][3] = vld[3] ? gpp[3][q] : (unsigned short)0;         \
        }                                                                   \
    }

#define MF_WRITE()                                                          \
    _Pragma("unroll")                                                       \
    for (int pass = 0; pass < 10; ++pass) {                                 \
        if (pass < 9 || lane < 49) {                                        \
            uint2 w;                                                        \
            w.x = (unsigned)vreg[pass][0] | ((unsigned)vreg[pass][1] << 16);\
            w.y = (unsigned)vreg[pass][2] | ((unsigned)vreg[pass][3] << 16);\
            *(uint2*)((char*)sp + dstw_[pass]) = w;                         \
        }                                                                   \
    }

#define MF_MFMA(AF)                                                         \
    _Pragma("unroll")                                                       \
    for (int dd = 0; dd < 9; ++dd) {                                        \
        const int d3 = dd / 3, d4 = dd - d3 * 3;                            \
        const int imm = (d3 * 27 + d4) * (L2S * 2);                         \
        _Pragma("unroll")                                                   \
        for (int j = 0; j < 7; ++j) {                                       \
            if (j < 6 || wave < 2) {                                        \
                const char* rp = (const char*)sp + (bpo_[j] + imm);         \
                uint2 p0 = *(const uint2*)rp;                               \
                uint2 p1 = *(const uint2*)(rp + 8);                         \
                union { unsigned u[4]; bf16x8 v; } cv;                      \
                cv.u[0] = p0.x; cv.u[1] = p0.y; cv.u[2] = p1.x; cv.u[3] = p1.y; \
                acc[j] = __builtin_amdgcn_mfma_f32_16x16x32_bf16((AF)[dd], cv.v, acc[j], 0, 0, 0); \
            }                                                               \
        }                                                                   \
    }

__global__ __launch_bounds__(512) void conv4d_mfma_l2(
    const unsigned short* __restrict__ x1, const unsigned short* __restrict__ Ablob,
    const float* __restrict__ bL2, unsigned short* __restrict__ x2)
{
    __shared__ alignas(16) unsigned short sp[L2ROWS * L2S]; // 52992 B
    const int f12 = blockIdx.x, g = blockIdx.y;
    const unsigned short* in = x1 + (size_t)blockIdx.z * 20 * NPOSQ;
    unsigned short* out = x2 + (size_t)blockIdx.z * 20 * NPOSQ;
    const int f1 = f12 / 25, f2 = f12 - f1 * 25;
    const int tid = threadIdx.x, wave = tid >> 6, lane = tid & 63;
    const int lo16 = lane & 15, kqg = (lane >> 4) << 3;

    for (int i = tid; i < L2ROWS * L2S / 2; i += 512) ((unsigned*)sp)[i] = 0u;

    f32x4 acc[7];
#pragma unroll
    for (int j = 0; j < 7; ++j) acc[j] = (f32x4){0.f, 0.f, 0.f, 0.f};
    const unsigned short* Ag = Ablob + (size_t)g * 27 * 512;

    MF_PRE();
    MF_CALC(0, g * 10, 90);
    MF_LOAD();

#pragma unroll 1
    for (int kstep = 0; kstep < 3; ++kstep) {
        __syncthreads();
        MF_WRITE();
        __syncthreads();
        const unsigned short* Abase = Ag + (size_t)(kstep * 9) * 512 + lane * 8;
        bf16x8 af[9];
#pragma unroll
        for (int dd = 0; dd < 9; ++dd)
            af[dd] = *(const bf16x8*)(Abase + dd * 512);
        if (kstep < 2) {
            MF_CALC(kstep + 1, g * 10, 90);
            MF_LOAD();
        }
        MF_MFMA(af);
    }

    unsigned short* ob = out + (size_t)f12 * 20 * 625 + g * 10 * 625;
    int t = wave;
    for (int j = 0; j < 7; ++j, t += 8) {
        if (t < 50) {
            int f3 = t >> 1, h = t & 1;
            int f4 = h * 16 + lo16;
            if (f4 < 25) {
#pragma unroll
                for (int r = 0; r < 4; ++r) {
                    int co = (lane >> 4) * 4 + r;
                    if (co < 10) {
                        float v = acc[j][r] + bL2[g * 10 + co];
                        ob[co * 625 + f3 * 25 + f4] = f2bf(fmaxf(v, 0.0f));
                    }
                }
            }
        }
    }
}

// Layer 3: K=180 (both groups), fused relu-sum, fp32 out to sbuf. Same T14 structure.
__global__ __launch_bounds__(512) void conv4d_mfma_l3(
    const unsigned short* __restrict__ x2, const unsigned short* __restrict__ Ablob3,
    const float* __restrict__ b3p, float* __restrict__ sbuf)
{
    __shared__ alignas(16) unsigned short sp[L2ROWS * L2S];
    const int f12 = blockIdx.x;
    const unsigned short* in = x2 + (size_t)blockIdx.z * 20 * NPOSQ;
    float* out = sbuf + (size_t)blockIdx.z * NPOSQ;
    const int f1 = f12 / 25, f2 = f12 - f1 * 25;
    const int tid = threadIdx.x, wave = tid >> 6, lane = tid & 63;
    const int lo16 = lane & 15, kqg = (lane >> 4) << 3;

    for (int i = tid; i < L2ROWS * L2S / 2; i += 512) ((unsigned*)sp)[i] = 0u;

    f32x4 acc[7];
#pragma unroll
    for (int j = 0; j < 7; ++j) acc[j] = (f32x4){0.f, 0.f, 0.f, 0.f};

    MF_PRE();
    MF_CALC(0, 0, 180);
    MF_LOAD();

#pragma unroll 1
    for (int kstep = 0; kstep < 6; ++kstep) {
        __syncthreads();
        MF_WRITE();
        __syncthreads();
        const unsigned short* Abase = Ablob3 + (size_t)(kstep * 9) * 512 + lane * 8;
        bf16x8 af[9];
#pragma unroll
        for (int dd = 0; dd < 9; ++dd)
            af[dd] = *(const bf16x8*)(Abase + dd * 512);
        if (kstep < 5) {
            MF_CALC(kstep + 1, 0, 180);
            MF_LOAD();
        }
        MF_MFMA(af);
    }

    const float b3v = b3p[0];
    if ((lane >> 4) == 0) {
        int t = wave;
        for (int j = 0; j < 7; ++j, t += 8) {
            if (t < 50) {
                int f3 = t >> 1, h = t & 1;
                int f4 = h * 16 + lo16;
                if (f4 < 25) {
                    float s0 = fmaxf(acc[j][0] + b3v, 0.0f);
                    float s1 = fmaxf(acc[j][1] + b3v, 0.0f);
                    out[f12 * 625 + f3 * 25 + f4] = s0 + s1;
                }
            }
        }
    }
}

// ---------------- launch ----------------
extern "C" void kernel_launch(void* const* d_in, const int* in_sizes, int n_in,
                              void* d_out, int out_size, void* d_ws, size_t ws_size,
                              hipStream_t stream)
{
    const float* fA = (const float*)d_in[0];
    const float* fB = (const float*)d_in[1];
    const float* W1 = (const float*)d_in[2];
    const float* b1 = (const float*)d_in[3];
    const float* W2 = (const float*)d_in[4];
    const float* b2 = (const float*)d_in[5];
    const float* W3 = (const float*)d_in[6];
    const float* b3 = (const float*)d_in[7];
    float* out = (float*)d_out;
    float* ws = (float*)d_ws;

    float* invA = ws + 0;        // 2500
    float* invB = ws + 2500;     // 2500
    float* rmax = ws + 5000;     // 2500
    float* cmax = ws + 7500;     // 2500
    float* W1P  = ws + 10000;    // 1620
    float* bL1  = ws + 11620;    // 20
    float* bL2  = ws + 11640;    // 20
    unsigned short* Ablob2 = (unsigned short*)(ws + 12000); // 27648 us
    unsigned short* Ablob3 = (unsigned short*)(ws + 25824); // 27648 us
    float* corr = ws + 40000;    // 1562500
    float* sbuf = ws + 1602500;  // 1562500
    unsigned short* x1b = (unsigned short*)(ws + 3165000);

    const size_t REQ = (size_t)34415000 * 4;
    const bool fused = ws_size >= REQ;
    unsigned short* x2b = fused ? (unsigned short*)(ws + 18790000)
                                : (unsigned short*)(ws + 7080000);

    hipLaunchKernelGGL(pack_misc_kernel, dim3(7), dim3(256), 0, stream,
                       W1, b1, b2, W1P, bL1, bL2);
    hipLaunchKernelGGL(pack_mfma_w2_kernel, dim3(14), dim3(256), 0, stream, W2, Ablob2);
    hipLaunchKernelGGL(pack_mfma_w3_kernel, dim3(14), dim3(256), 0, stream, W3, Ablob3);
    hipLaunchKernelGGL(invnorm_kernel, dim3(10, 2), dim3(256), 0, stream, fA, fB, invA, invB);
    hipLaunchKernelGGL(corr_gemm_kernel, dim3(10, 10, 4), dim3(256), 0, stream,
                       fA, fB, invA, invB, corr);
    hipLaunchKernelGGL(rowmax_kernel, dim3(625), dim3(256), 0, stream, corr, rmax);
    hipLaunchKernelGGL(colmax_kernel, dim3(4, 5), dim3(128), 0, stream, corr, cmax);
    hipLaunchKernelGGL(mm_apply_kernel, dim3(6104), dim3(256), 0, stream, corr, rmax, cmax, corr);

    if (fused) {
        hipLaunchKernelGGL(conv4d_l1, dim3(625, 1, NB), dim3(192), 0, stream, corr, W1P, bL1, x1b);
        hipLaunchKernelGGL(conv4d_mfma_l2, dim3(625, 2, NB), dim3(512), 0, stream,
                           x1b, Ablob2, bL2, x2b);
        hipLaunchKernelGGL(conv4d_mfma_l3, dim3(625, 1, NB), dim3(512), 0, stream,
                           x2b, Ablob3, b3, sbuf);
    } else {
        for (int b = 0; b < NB; ++b) {
            hipLaunchKernelGGL(conv4d_l1, dim3(625, 1, 1), dim3(192), 0, stream,
                               corr + (size_t)b * NPOSQ, W1P, bL1, x1b);
            hipLaunchKernelGGL(conv4d_mfma_l2, dim3(625, 2, 1), dim3(512), 0, stream,
                               x1b, Ablob2, bL2, x2b);
            hipLaunchKernelGGL(conv4d_mfma_l3, dim3(625, 1, 1), dim3(512), 0, stream,
                               x2b, Ablob3, b3, sbuf + (size_t)b * NPOSQ);
        }
    }

    hipLaunchKernelGGL(rowmax_kernel, dim3(625), dim3(256), 0, stream, sbuf, rmax);
    hipLaunchKernelGGL(colmax_kernel, dim3(4, 5), dim3(128), 0, stream, sbuf, cmax);
    hipLaunchKernelGGL(mm_apply_kernel, dim3(6104), dim3(256), 0, stream, sbuf, rmax, cmax, out);
}

// Round 12
// 1105.037 us; speedup vs baseline: 1.4356x; 1.0044x over previous
//
#include <hip/hip_runtime.h>
#include <math.h>

#define HWQ 625      // 25*25
#define NPOSQ 390625 // 625*625
#define NB 4
#define NCH 1024

typedef __attribute__((ext_vector_type(8))) short bf16x8;
typedef __attribute__((ext_vector_type(4))) float f32x4;
typedef __attribute__((ext_vector_type(16))) float f32x16;

__device__ inline unsigned short f2bf(float x) {
    union { float f; unsigned int u; } c; c.f = x;
    unsigned int u = c.u;
    return (unsigned short)((u + 0x7fffu + ((u >> 16) & 1u)) >> 16); // RNE
}

// ---------------- pack: W1P [9e][9t][20co], bias dups ----------------
__global__ void pack_misc_kernel(const float* __restrict__ W1, const float* __restrict__ b1,
                                 const float* __restrict__ b2,
                                 float* __restrict__ W1P, float* __restrict__ bL1,
                                 float* __restrict__ bL2)
{
    int t = blockIdx.x * blockDim.x + threadIdx.x;
    if (t < 1620) {
        int co = t % 20; int r = t / 20; int e = r / 9, t34 = r % 9;
        W1P[t] = (co < 10) ? W1[co * 81 + e * 9 + t34] : W1[(co - 10) * 81 + t34 * 9 + e];
    }
    if (t < 20) { bL1[t] = b1[t % 10]; bL2[t] = b2[t % 10]; }
}

// ---------------- pack layer-2 weights into 16x16x32 A-fragment order ----------------
__global__ void pack_mfma_w2_kernel(const float* __restrict__ W2,
                                    unsigned short* __restrict__ Ablob)
{
    int t = blockIdx.x * blockDim.x + threadIdx.x;
    if (t >= 54 * 64) return;
    int frag = t >> 6, lane = t & 63;
    int g = frag / 27; int r1 = frag % 27; int kstep = r1 / 9; int dd = r1 % 9;
    int d3 = dd / 3, d4 = dd % 3;
    int co = lane & 15;
    unsigned short v[8];
#pragma unroll
    for (int j = 0; j < 8; ++j) {
        int k = kstep * 32 + ((lane >> 4) << 3) + j;
        float w = 0.0f;
        if (co < 10 && k < 90) {
            int ci = k / 9, e = k % 9, d1 = e / 3, d2 = e % 3;
            int tap = (g == 0) ? (d1 * 27 + d2 * 9 + d3 * 3 + d4)
                               : (d3 * 27 + d4 * 9 + d1 * 3 + d2);
            w = W2[(co * 10 + ci) * 81 + tap];
        }
        v[j] = f2bf(w);
    }
    uint4 val;
    val.x = (unsigned)v[0] | ((unsigned)v[1] << 16);
    val.y = (unsigned)v[2] | ((unsigned)v[3] << 16);
    val.z = (unsigned)v[4] | ((unsigned)v[5] << 16);
    val.w = (unsigned)v[6] | ((unsigned)v[7] << 16);
    *(uint4*)(Ablob + (size_t)frag * 512 + lane * 8) = val;
}

// ---------------- pack layer-3 weights for 32x32x16, dd-in-M ----------------
// A3[m=g*9+dd (18 used of 32)][k=ch*9+e (180 used of 192)], zero if ch/10 != g.
// frag = chunk*2 + s (chunk<6, s<2); lane: m = lane&31, k = chunk*32+s*16+(lane>>5)*8+j.
__global__ void pack_mfma_w3_kernel(const float* __restrict__ W3,
                                    unsigned short* __restrict__ Ablob3)
{
    int t = blockIdx.x * blockDim.x + threadIdx.x;
    if (t >= 12 * 64) return;
    int frag = t >> 6, lane = t & 63;
    int chunk = frag >> 1, s = frag & 1;
    int m = lane & 31;
    unsigned short v[8];
#pragma unroll
    for (int j = 0; j < 8; ++j) {
        int k = chunk * 32 + s * 16 + ((lane >> 5) << 3) + j;
        float w = 0.0f;
        if (m < 18 && k < 180) {
            int g = m / 9, dd = m % 9;
            int ch = k / 9, e = k % 9;
            if (ch / 10 == g) {
                int ci = ch % 10;
                int d1 = e / 3, d2 = e % 3, d3 = dd / 3, d4 = dd % 3;
                int tap = (g == 0) ? (d1 * 27 + d2 * 9 + d3 * 3 + d4)
                                   : (d3 * 27 + d4 * 9 + d1 * 3 + d2);
                w = W3[ci * 81 + tap];
            }
        }
        v[j] = f2bf(w);
    }
    uint4 val;
    val.x = (unsigned)v[0] | ((unsigned)v[1] << 16);
    val.y = (unsigned)v[2] | ((unsigned)v[3] << 16);
    val.z = (unsigned)v[4] | ((unsigned)v[5] << 16);
    val.w = (unsigned)v[6] | ((unsigned)v[7] << 16);
    *(uint4*)(Ablob3 + (size_t)frag * 512 + lane * 8) = val;
}

// ---------------- inverse L2 norms over channel dim ----------------
__global__ void invnorm_kernel(const float* __restrict__ fA, const float* __restrict__ fB,
                               float* __restrict__ invA, float* __restrict__ invB)
{
    int idx = blockIdx.x * blockDim.x + threadIdx.x;
    if (idx >= NB * HWQ) return;
    const float* f = blockIdx.y ? fB : fA;
    float* o = blockIdx.y ? invB : invA;
    int b = idx / HWQ, m = idx - b * HWQ;
    const float* p = f + (size_t)b * NCH * HWQ + m;
    float s = 0.f;
    for (int c = 0; c < NCH; c += 4) {
        float x0 = p[(c + 0) * HWQ], x1 = p[(c + 1) * HWQ];
        float x2 = p[(c + 2) * HWQ], x3 = p[(c + 3) * HWQ];
        s += x0 * x0 + x1 * x1 + x2 * x2 + x3 * x3;
    }
    o[idx] = 1.0f / sqrtf(s + 1e-6f);
}

// ---------------- correlation GEMM ----------------
__global__ __launch_bounds__(256) void corr_gemm_kernel(
    const float* __restrict__ fA, const float* __restrict__ fB,
    const float* __restrict__ invA, const float* __restrict__ invB,
    float* __restrict__ corr)
{
    __shared__ float As[16][64];
    __shared__ float Bs[16][64];
    const int b = blockIdx.z;
    const int m0 = blockIdx.y * 64, n0 = blockIdx.x * 64;
    const int tid = threadIdx.x;
    const int tx = tid & 15, ty = tid >> 4;
    float acc[4][4] = {};
    const float* Ab = fA + (size_t)b * NCH * HWQ;
    const float* Bb = fB + (size_t)b * NCH * HWQ;
    for (int k0 = 0; k0 < NCH; k0 += 16) {
        for (int i = tid; i < 1024; i += 256) {
            int k = i >> 6, mm = i & 63;
            int gm = m0 + mm, gn = n0 + mm;
            As[k][mm] = (gm < HWQ) ? Ab[(k0 + k) * HWQ + gm] : 0.0f;
            Bs[k][mm] = (gn < HWQ) ? Bb[(k0 + k) * HWQ + gn] : 0.0f;
        }
        __syncthreads();
#pragma unroll
        for (int k = 0; k < 16; ++k) {
            float4 a4 = *(const float4*)&As[k][ty * 4];
            float4 b4 = *(const float4*)&Bs[k][tx * 4];
            float av[4] = {a4.x, a4.y, a4.z, a4.w};
            float bv[4] = {b4.x, b4.y, b4.z, b4.w};
#pragma unroll
            for (int i = 0; i < 4; ++i)
#pragma unroll
                for (int j = 0; j < 4; ++j)
                    acc[i][j] = fmaf(av[i], bv[j], acc[i][j]);
        }
        __syncthreads();
    }
#pragma unroll
    for (int i = 0; i < 4; ++i) {
        int m = m0 + ty * 4 + i;
        if (m >= HWQ) continue;
        float ia = invA[b * HWQ + m];
#pragma unroll
        for (int j = 0; j < 4; ++j) {
            int n = n0 + tx * 4 + j;
            if (n >= HWQ) continue;
            float v = acc[i][j] * ia * invB[b * HWQ + n];
            v = fmaxf(v, 0.0f);
            v = v / sqrtf(v * v + 1e-6f);
            corr[((size_t)b * HWQ + m) * HWQ + n] = v;
        }
    }
}

// ---------------- mutual matching helpers ----------------
__global__ void rowmax_kernel(const float* __restrict__ s, float* __restrict__ rmax)
{
    int row = blockIdx.x * 4 + (threadIdx.x >> 6);
    int lane = threadIdx.x & 63;
    if (row >= NB * HWQ) return;
    const float* p = s + (size_t)row * HWQ;
    float v = -1e30f;
    for (int n = lane; n < HWQ; n += 64) v = fmaxf(v, p[n]);
    for (int off = 32; off; off >>= 1) v = fmaxf(v, __shfl_xor(v, off));
    if (lane == 0) rmax[row] = v;
}

__global__ void colmax_kernel(const float* __restrict__ s, float* __restrict__ cmax)
{
    int b = blockIdx.x;
    int col = blockIdx.y * 128 + threadIdx.x;
    if (col >= HWQ) return;
    const float* p = s + (size_t)b * NPOSQ + col;
    float v = -1e30f;
    for (int m = 0; m < HWQ; ++m) v = fmaxf(v, p[m * HWQ]);
    cmax[b * HWQ + col] = v;
}

__global__ void mm_apply_kernel(const float* __restrict__ s, const float* __restrict__ rmax,
                                const float* __restrict__ cmax, float* __restrict__ out)
{
    int idx = blockIdx.x * blockDim.x + threadIdx.x;
    if (idx >= NB * NPOSQ) return;
    int b = idx / NPOSQ, rem = idx - b * NPOSQ;
    int m = rem / HWQ, n = rem - m * HWQ;
    float v = s[idx];
    out[idx] = v * v * v / ((rmax[b * HWQ + m] + 1e-5f) * (cmax[b * HWQ + n] + 1e-5f));
}

// ---------------- layer 1: VALU conv, weights in LDS ----------------
// OUTPUT LAYOUT: x1[f12][co(20)][625]
__global__ __launch_bounds__(192) void conv4d_l1(
    const float* __restrict__ corr, const float* __restrict__ W1P,
    const float* __restrict__ bL1, unsigned short* __restrict__ x1)
{
    __shared__ float sp[9 * 784]; // 9 x 28 x 28
    __shared__ float wl[1620];
    const int f12 = blockIdx.x;
    const float* in = corr + (size_t)blockIdx.z * NPOSQ;
    unsigned short* out = x1 + (size_t)blockIdx.z * 20 * NPOSQ;
    const int f1 = f12 / 25, f2 = f12 - f1 * 25;
    const int tid = threadIdx.x;

    for (int i = tid; i < 9 * 784; i += 192) sp[i] = 0.0f;
    for (int i = tid; i < 1620; i += 192) wl[i] = W1P[i];

    const int tt = (tid < 169) ? tid : 0;
    const int ty = tt / 13, tx = tt - ty * 13;
    const int r0 = ty * 2, c0 = tx * 2;

    float acc[20][4];
#pragma unroll
    for (int co = 0; co < 20; ++co) {
        float bv = bL1[co];
        acc[co][0] = bv; acc[co][1] = bv; acc[co][2] = bv; acc[co][3] = bv;
    }

    __syncthreads();
    for (int i = tid; i < 5625; i += 192) {
        int e = i / 625, q = i - e * 625;
        int d1 = e / 3, d2 = e - d1 * 3;
        int f1n = f1 + d1 - 1, f2n = f2 + d2 - 1;
        float v = 0.0f;
        if (((unsigned)f1n < 25u) & ((unsigned)f2n < 25u))
            v = in[(f1n * 25 + f2n) * HWQ + q];
        int rr = q / 25, cc = q - rr * 25;
        sp[e * 784 + (rr + 1) * 28 + (cc + 1)] = v;
    }
    __syncthreads();

#pragma unroll 1
    for (int e = 0; e < 9; ++e) {
        float win[16];
        const int base = e * 784 + r0 * 28 + c0;
#pragma unroll
        for (int a = 0; a < 4; ++a)
#pragma unroll
            for (int bb = 0; bb < 4; ++bb)
                win[a * 4 + bb] = sp[base + a * 28 + bb];
#pragma unroll
        for (int t34 = 0; t34 < 9; ++t34) {
            int d3 = t34 / 3, d4 = t34 - d3 * 3;
            float x0 = win[d3 * 4 + d4], x1v = win[d3 * 4 + d4 + 1];
            float x2v = win[(d3 + 1) * 4 + d4], x3v = win[(d3 + 1) * 4 + d4 + 1];
            const float* wp = wl + (e * 9 + t34) * 20;
#pragma unroll
            for (int c4 = 0; c4 < 5; ++c4) {
                float4 w4 = *(const float4*)(wp + c4 * 4);
                float wv[4] = {w4.x, w4.y, w4.z, w4.w};
#pragma unroll
                for (int q4 = 0; q4 < 4; ++q4) {
                    int co = c4 * 4 + q4;
                    acc[co][0] = fmaf(x0, wv[q4], acc[co][0]);
                    acc[co][1] = fmaf(x1v, wv[q4], acc[co][1]);
                    acc[co][2] = fmaf(x2v, wv[q4], acc[co][2]);
                    acc[co][3] = fmaf(x3v, wv[q4], acc[co][3]);
                }
            }
        }
    }

    if (tid < 169) {
        unsigned short* ob = out + (size_t)f12 * 20 * 625;
#pragma unroll
        for (int co = 0; co < 20; ++co) {
            unsigned short* op = ob + co * 625;
#pragma unroll
            for (int i = 0; i < 2; ++i)
#pragma unroll
                for (int j = 0; j < 2; ++j) {
                    int f3 = r0 + i, f4 = c0 + j;
                    if (f3 < 25 && f4 < 25)
                        op[f3 * 25 + f4] = f2bf(fmaxf(acc[co][i * 2 + j], 0.0f));
                }
        }
    }
}

// ---------------- layer 2: MFMA conv 16x16x32 (R9 structure: direct stage) ----------
#define L2S 36
#define L2ROWS 736

__global__ __launch_bounds__(512) void conv4d_mfma_l2(
    const unsigned short* __restrict__ x1, const unsigned short* __restrict__ Ablob,
    const float* __restrict__ bL2, unsigned short* __restrict__ x2)
{
    __shared__ alignas(16) unsigned short sp[L2ROWS * L2S]; // 52992 B
    const int f12 = blockIdx.x, g = blockIdx.y;
    const unsigned short* in = x1 + (size_t)blockIdx.z * 20 * NPOSQ;
    unsigned short* out = x2 + (size_t)blockIdx.z * 20 * NPOSQ;
    const int f1 = f12 / 25, f2 = f12 - f1 * 25;
    const int tid = threadIdx.x, wave = tid >> 6, lane = tid & 63;
    const int lo16 = lane & 15, kqg = (lane >> 4) << 3;

    for (int i = tid; i < L2ROWS * L2S / 2; i += 512) ((unsigned*)sp)[i] = 0u;

    f32x4 acc[7];
#pragma unroll
    for (int j = 0; j < 7; ++j) acc[j] = (f32x4){0.f, 0.f, 0.f, 0.f};
    const unsigned short* Ag = Ablob + (size_t)g * 27 * 512;

    int dstw_[10];
#pragma unroll
    for (int pass = 0; pass < 10; ++pass) {
        int idx = pass * 64 + lane;
        int rr = idx / 25, cc = idx - rr * 25;
        dstw_[pass] = ((rr + 1) * 27 + cc + 1) * (L2S * 2) + wave * 8;
    }
    unsigned bpo_[7];
#pragma unroll
    for (int j = 0; j < 7; ++j) {
        int t = wave + j * 8;
        int f3 = t >> 1, h = t & 1;
        bpo_[j] = (unsigned)(((f3 * 27 + h * 16 + lo16) * L2S + kqg) * 2);
    }

#pragma unroll 1
    for (int kstep = 0; kstep < 3; ++kstep) {
        const unsigned short* gpp[4];
        bool vld[4];
        {
            int ksb = kstep * 32;
#pragma unroll
            for (int i2 = 0; i2 < 4; ++i2) {
                int cie = ksb + wave * 4 + i2;
                int e = cie % 9;
                int f1n = f1 + e / 3 - 1, f2n = f2 + (e % 3) - 1;
                bool valid = (cie < 90) & ((unsigned)f1n < 25u) & ((unsigned)f2n < 25u);
                int pidx = valid ? ((f1n * 25 + f2n) * 20 + g * 10 + cie / 9) : 0;
                gpp[i2] = in + (size_t)pidx * 625;
                vld[i2] = valid;
            }
        }
        __syncthreads();
#pragma unroll
        for (int pass = 0; pass < 10; ++pass) {
            if (pass < 9 || lane < 49) {
                int q = pass * 64 + lane;
                unsigned short v0 = vld[0] ? gpp[0][q] : (unsigned short)0;
                unsigned short v1 = vld[1] ? gpp[1][q] : (unsigned short)0;
                unsigned short v2 = vld[2] ? gpp[2][q] : (unsigned short)0;
                unsigned short v3 = vld[3] ? gpp[3][q] : (unsigned short)0;
                uint2 w;
                w.x = (unsigned)v0 | ((unsigned)v1 << 16);
                w.y = (unsigned)v2 | ((unsigned)v3 << 16);
                *(uint2*)((char*)sp + dstw_[pass]) = w;
            }
        }
        __syncthreads();
        const unsigned short* Abase = Ag + (size_t)(kstep * 9) * 512 + lane * 8;
        bf16x8 afA = *(const bf16x8*)(Abase);
#pragma unroll
        for (int dd = 0; dd < 9; ++dd) {
            bf16x8 afN = (dd < 8) ? *(const bf16x8*)(Abase + (dd + 1) * 512) : afA;
            const int d3 = dd / 3, d4 = dd - d3 * 3;
            const int imm = (d3 * 27 + d4) * (L2S * 2);
#pragma unroll
            for (int j = 0; j < 7; ++j) {
                if (j < 6 || wave < 2) {
                    const char* rp = (const char*)sp + (bpo_[j] + imm);
                    uint2 p0 = *(const uint2*)rp;
                    uint2 p1 = *(const uint2*)(rp + 8);
                    union { unsigned u[4]; bf16x8 v; } cv;
                    cv.u[0] = p0.x; cv.u[1] = p0.y; cv.u[2] = p1.x; cv.u[3] = p1.y;
                    acc[j] = __builtin_amdgcn_mfma_f32_16x16x32_bf16(afA, cv.v, acc[j], 0, 0, 0);
                }
            }
            afA = afN;
        }
    }

    unsigned short* ob = out + (size_t)f12 * 20 * 625 + g * 10 * 625;
    int t = wave;
    for (int j = 0; j < 7; ++j, t += 8) {
        if (t < 50) {
            int f3 = t >> 1, h = t & 1;
            int f4 = h * 16 + lo16;
            if (f4 < 25) {
#pragma unroll
                for (int r = 0; r < 4; ++r) {
                    int co = (lane >> 4) * 4 + r;
                    if (co < 10) {
                        float v = acc[j][r] + bL2[g * 10 + co];
                        ob[co * 625 + f3 * 25 + f4] = f2bf(fmaxf(v, 0.0f));
                    }
                }
            }
        }
    }
}

// ---------------- layer 3: 32x32x16 MFMA, dd-in-M ----------------
// D[m=(g,dd) 18][q' halo(736=23x32)] = A3[m][k=(ch,e) 180] * Xp[k][q'] (unshifted B!).
// Epilogue: out[q] = relu(sum_dd D[dd][hq(q,dd)] + b3) + relu(sum_dd D[9+dd][hq] + b3).
// D (f32 18x736 = 52992B) exactly reuses sp. 9.8x fewer MFMA than the M=2 form.
__global__ __launch_bounds__(512) void conv4d_mfma_l3(
    const unsigned short* __restrict__ x2, const unsigned short* __restrict__ Ablob3,
    const float* __restrict__ b3p, float* __restrict__ sbuf)
{
    __shared__ alignas(16) unsigned short sp[L2ROWS * L2S]; // 52992 B
    const int f12 = blockIdx.x;
    const unsigned short* in = x2 + (size_t)blockIdx.z * 20 * NPOSQ;
    float* out = sbuf + (size_t)blockIdx.z * NPOSQ;
    const int f1 = f12 / 25, f2 = f12 - f1 * 25;
    const int tid = threadIdx.x, wave = tid >> 6, lane = tid & 63;
    const int col = lane & 31, kg8 = (lane >> 5) << 3;

    for (int i = tid; i < L2ROWS * L2S / 2; i += 512) ((unsigned*)sp)[i] = 0u;

    f32x16 acc0 = {}, acc1 = {}, acc2 = {};
    const int t0 = wave, t1 = wave + 8, t2 = wave + 16; // n-tiles (23 total)
    const bool has2 = (t2 < 23);

    int dstw_[10];
#pragma unroll
    for (int pass = 0; pass < 10; ++pass) {
        int idx = pass * 64 + lane;
        int rr = idx / 25, cc = idx - rr * 25;
        dstw_[pass] = ((rr + 1) * 27 + cc + 1) * (L2S * 2) + wave * 8;
    }
    const unsigned short* b0p = sp + (t0 * 32 + col) * L2S + kg8;
    const unsigned short* b1p = sp + (t1 * 32 + col) * L2S + kg8;
    const unsigned short* b2p = sp + (t2 * 32 + col) * L2S + kg8;

#pragma unroll 1
    for (int chunk = 0; chunk < 6; ++chunk) {
        const unsigned short* gpp[4];
        bool vld[4];
        {
            int ksb = chunk * 32;
#pragma unroll
            for (int i2 = 0; i2 < 4; ++i2) {
                int cie = ksb + wave * 4 + i2;
                int e = cie % 9;
                int f1n = f1 + e / 3 - 1, f2n = f2 + (e % 3) - 1;
                bool valid = (cie < 180) & ((unsigned)f1n < 25u) & ((unsigned)f2n < 25u);
                int pidx = valid ? ((f1n * 25 + f2n) * 20 + cie / 9) : 0;
                gpp[i2] = in + (size_t)pidx * 625;
                vld[i2] = valid;
            }
        }
        __syncthreads();
#pragma unroll
        for (int pass = 0; pass < 10; ++pass) {
            if (pass < 9 || lane < 49) {
                int q = pass * 64 + lane;
                unsigned short v0 = vld[0] ? gpp[0][q] : (unsigned short)0;
                unsigned short v1 = vld[1] ? gpp[1][q] : (unsigned short)0;
                unsigned short v2 = vld[2] ? gpp[2][q] : (unsigned short)0;
                unsigned short v3 = vld[3] ? gpp[3][q] : (unsigned short)0;
                uint2 w;
                w.x = (unsigned)v0 | ((unsigned)v1 << 16);
                w.y = (unsigned)v2 | ((unsigned)v3 << 16);
                *(uint2*)((char*)sp + dstw_[pass]) = w;
            }
        }
        __syncthreads();
        bf16x8 a0 = *(const bf16x8*)(Ablob3 + (size_t)(chunk * 2 + 0) * 512 + lane * 8);
        bf16x8 a1 = *(const bf16x8*)(Ablob3 + (size_t)(chunk * 2 + 1) * 512 + lane * 8);
        bf16x8 b;
        b = *(const bf16x8*)(b0p);
        acc0 = __builtin_amdgcn_mfma_f32_32x32x16_bf16(a0, b, acc0, 0, 0, 0);
        b = *(const bf16x8*)(b0p + 16);
        acc0 = __builtin_amdgcn_mfma_f32_32x32x16_bf16(a1, b, acc0, 0, 0, 0);
        b = *(const bf16x8*)(b1p);
        acc1 = __builtin_amdgcn_mfma_f32_32x32x16_bf16(a0, b, acc1, 0, 0, 0);
        b = *(const bf16x8*)(b1p + 16);
        acc1 = __builtin_amdgcn_mfma_f32_32x32x16_bf16(a1, b, acc1, 0, 0, 0);
        if (has2) {
            b = *(const bf16x8*)(b2p);
            acc2 = __builtin_amdgcn_mfma_f32_32x32x16_bf16(a0, b, acc2, 0, 0, 0);
            b = *(const bf16x8*)(b2p + 16);
            acc2 = __builtin_amdgcn_mfma_f32_32x32x16_bf16(a1, b, acc2, 0, 0, 0);
        }
    }

    // write D[m][q'] (f32) into sp
    __syncthreads();
    float* D = (float*)sp;
#pragma unroll
    for (int r = 0; r < 16; ++r) {
        int m = (r & 3) + 8 * (r >> 2) + 4 * (lane >> 5);
        if (m < 18) {
            D[m * L2ROWS + t0 * 32 + col] = acc0[r];
            D[m * L2ROWS + t1 * 32 + col] = acc1[r];
            if (has2) D[m * L2ROWS + t2 * 32 + col] = acc2[r];
        }
    }
    __syncthreads();

    const float b3v = b3p[0];
    for (int q = tid; q < 625; q += 512) {
        int f3 = q / 25, f4 = q - f3 * 25;
        float s0 = 0.f, s1 = 0.f;
#pragma unroll
        for (int dd = 0; dd < 9; ++dd) {
            int d3 = dd / 3, d4 = dd - d3 * 3;
            int hq = (f3 + d3) * 27 + (f4 + d4);
            s0 += D[dd * L2ROWS + hq];
            s1 += D[(9 + dd) * L2ROWS + hq];
        }
        out[f12 * 625 + q] = fmaxf(s0 + b3v, 0.0f) + fmaxf(s1 + b3v, 0.0f);
    }
}

// ---------------- launch ----------------
extern "C" void kernel_launch(void* const* d_in, const int* in_sizes, int n_in,
                              void* d_out, int out_size, void* d_ws, size_t ws_size,
                              hipStream_t stream)
{
    const float* fA = (const float*)d_in[0];
    const float* fB = (const float*)d_in[1];
    const float* W1 = (const float*)d_in[2];
    const float* b1 = (const float*)d_in[3];
    const float* W2 = (const float*)d_in[4];
    const float* b2 = (const float*)d_in[5];
    const float* W3 = (const float*)d_in[6];
    const float* b3 = (const float*)d_in[7];
    float* out = (float*)d_out;
    float* ws = (float*)d_ws;

    float* invA = ws + 0;        // 2500
    float* invB = ws + 2500;     // 2500
    float* rmax = ws + 5000;     // 2500
    float* cmax = ws + 7500;     // 2500
    float* W1P  = ws + 10000;    // 1620
    float* bL1  = ws + 11620;    // 20
    float* bL2  = ws + 11640;    // 20
    unsigned short* Ablob2 = (unsigned short*)(ws + 12000); // 27648 us
    unsigned short* Ablob3 = (unsigned short*)(ws + 25824); // 6144 us
    float* corr = ws + 40000;    // 1562500
    float* sbuf = ws + 1602500;  // 1562500
    unsigned short* x1b = (unsigned short*)(ws + 3165000);

    const size_t REQ = (size_t)34415000 * 4;
    const bool fused = ws_size >= REQ;
    unsigned short* x2b = fused ? (unsigned short*)(ws + 18790000)
                                : (unsigned short*)(ws + 7080000);

    hipLaunchKernelGGL(pack_misc_kernel, dim3(7), dim3(256), 0, stream,
                       W1, b1, b2, W1P, bL1, bL2);
    hipLaunchKernelGGL(pack_mfma_w2_kernel, dim3(14), dim3(256), 0, stream, W2, Ablob2);
    hipLaunchKernelGGL(pack_mfma_w3_kernel, dim3(3), dim3(256), 0, stream, W3, Ablob3);
    hipLaunchKernelGGL(invnorm_kernel, dim3(10, 2), dim3(256), 0, stream, fA, fB, invA, invB);
    hipLaunchKernelGGL(corr_gemm_kernel, dim3(10, 10, 4), dim3(256), 0, stream,
                       fA, fB, invA, invB, corr);
    hipLaunchKernelGGL(rowmax_kernel, dim3(625), dim3(256), 0, stream, corr, rmax);
    hipLaunchKernelGGL(colmax_kernel, dim3(4, 5), dim3(128), 0, stream, corr, cmax);
    hipLaunchKernelGGL(mm_apply_kernel, dim3(6104), dim3(256), 0, stream, corr, rmax, cmax, corr);

    if (fused) {
        hipLaunchKernelGGL(conv4d_l1, dim3(625, 1, NB), dim3(192), 0, stream, corr, W1P, bL1, x1b);
        hipLaunchKernelGGL(conv4d_mfma_l2, dim3(625, 2, NB), dim3(512), 0, stream,
                           x1b, Ablob2, bL2, x2b);
        hipLaunchKernelGGL(conv4d_mfma_l3, dim3(625, 1, NB), dim3(512), 0, stream,
                           x2b, Ablob3, b3, sbuf);
    } else {
        for (int b = 0; b < NB; ++b) {
            hipLaunchKernelGGL(conv4d_l1, dim3(625, 1, 1), dim3(192), 0, stream,
                               corr + (size_t)b * NPOSQ, W1P, bL1, x1b);
            hipLaunchKernelGGL(conv4d_mfma_l2, dim3(625, 2, 1), dim3(512), 0, stream,
                               x1b, Ablob2, bL2, x2b);
            hipLaunchKernelGGL(conv4d_mfma_l3, dim3(625, 1, 1), dim3(512), 0, stream,
                               x2b, Ablob3, b3, sbuf + (size_t)b * NPOSQ);
        }
    }

    hipLaunchKernelGGL(rowmax_kernel, dim3(625), dim3(256), 0, stream, sbuf, rmax);
    hipLaunchKernelGGL(colmax_kernel, dim3(4, 5), dim3(128), 0, stream, sbuf, cmax);
    hipLaunchKernelGGL(mm_apply_kernel, dim3(6104), dim3(256), 0, stream, sbuf, rmax, cmax, out);
}